// Round 1
// baseline (173.276 us; speedup 1.0000x reference)
//
#include <hip/hip_runtime.h>

// entmax-1.5 n-section loss for X:(n=4096, c=32000) fp32, target:(n,) int.
//
// Math: Xs = X/2; tau in [mx-1, mx] narrowed by 9 iters of 4-section search on
// f(tau) = sum relu(Xs - tau)^2 - 1 (decreasing). Since lo >= mx-1 always,
// ALL evaluations and the final p only involve elements with Xs > mx-1
// (~200 of 32000 for gaussian rows). So: cache the row in registers (one HBM
// pass), find max, gather candidates to LDS, and let one wave do the search.

#define NTHR 1024
#define VPT4 8          // float4 per thread: 8*4*1024 = 32768 >= 32000
#define CAP  8192       // candidate LDS capacity (expected ~200; >40 sigma)
#define NITER 9

__global__ __launch_bounds__(NTHR, 8)
void entmax_row_kernel(const float* __restrict__ X,
                       const int* __restrict__ target,
                       float* __restrict__ row_loss,
                       int c) {
    const int r    = blockIdx.x;
    const int tid  = threadIdx.x;
    const int wave = tid >> 6;
    const int lane = tid & 63;
    const float* __restrict__ Xr = X + (size_t)r * (size_t)c;

    __shared__ float s_red[16];
    __shared__ float s_r3[3][16];
    __shared__ float s_bcast[4];
    __shared__ int   s_cnt;
    __shared__ float cand[CAP];

    const int c4 = c >> 2;

    // ---- load row into registers (Xs = 0.5*X), coalesced float4 ----
    float4 v[VPT4];
    #pragma unroll
    for (int k = 0; k < VPT4; ++k) {
        const int i4 = tid + k * NTHR;
        if (i4 < c4) {
            const float4 t4 = ((const float4*)Xr)[i4];
            v[k].x = 0.5f * t4.x; v[k].y = 0.5f * t4.y;
            v[k].z = 0.5f * t4.z; v[k].w = 0.5f * t4.w;
        } else {
            v[k].x = v[k].y = v[k].z = v[k].w = -1e30f;
        }
    }
    // scalar tail (c not multiple of 4) — c=32000 is, but keep it general
    float tail = -1e30f;
    const int ti = (c4 << 2) + tid;
    if (ti < c) tail = 0.5f * Xr[ti];

    // ---- block max of Xs ----
    float m = tail;
    #pragma unroll
    for (int k = 0; k < VPT4; ++k)
        m = fmaxf(m, fmaxf(fmaxf(v[k].x, v[k].y), fmaxf(v[k].z, v[k].w)));
    #pragma unroll
    for (int off = 32; off > 0; off >>= 1)
        m = fmaxf(m, __shfl_xor(m, off));
    if (lane == 0) s_red[wave] = m;
    if (tid == 0) s_cnt = 0;
    __syncthreads();
    if (tid == 0) {
        float mm = s_red[0];
        for (int i = 1; i < 16; ++i) mm = fmaxf(mm, s_red[i]);
        s_bcast[0] = mm;
    }
    __syncthreads();
    const float mx = s_bcast[0];
    const float t0 = mx - 1.0f;     // tau >= t0 forever => only Xs > t0 matter

    // ---- gather candidates (Xs > t0) into LDS ----
    int cnt = (tail > t0) ? 1 : 0;
    #pragma unroll
    for (int k = 0; k < VPT4; ++k)
        cnt += (v[k].x > t0) + (v[k].y > t0) + (v[k].z > t0) + (v[k].w > t0);
    int pos = 0;
    if (cnt > 0) pos = atomicAdd(&s_cnt, cnt);
    #pragma unroll
    for (int k = 0; k < VPT4; ++k) {
        if (v[k].x > t0) { if (pos < CAP) cand[pos] = v[k].x; ++pos; }
        if (v[k].y > t0) { if (pos < CAP) cand[pos] = v[k].y; ++pos; }
        if (v[k].z > t0) { if (pos < CAP) cand[pos] = v[k].z; ++pos; }
        if (v[k].w > t0) { if (pos < CAP) cand[pos] = v[k].w; ++pos; }
    }
    if (tail > t0) { if (pos < CAP) cand[pos] = tail; ++pos; }
    __syncthreads();
    const int total = s_cnt;

    if (total <= CAP) {
        // ---- fast path: single wave runs the whole search on LDS candidates ----
        if (wave == 0) {
            float lo = t0, hi = mx;
            for (int it = 0; it < NITER; ++it) {
                const float w  = (hi - lo) * 0.25f;
                const float t1 = lo + w, t2 = lo + 2.0f * w, t3 = lo + 3.0f * w;
                float f1 = 0.f, f2 = 0.f, f3 = 0.f;
                for (int i = lane; i < total; i += 64) {
                    const float x = cand[i];
                    const float d1 = fmaxf(x - t1, 0.f); f1 = fmaf(d1, d1, f1);
                    const float d2 = fmaxf(x - t2, 0.f); f2 = fmaf(d2, d2, f2);
                    const float d3 = fmaxf(x - t3, 0.f); f3 = fmaf(d3, d3, f3);
                }
                #pragma unroll
                for (int off = 32; off > 0; off >>= 1) {
                    f1 += __shfl_xor(f1, off);
                    f2 += __shfl_xor(f2, off);
                    f3 += __shfl_xor(f3, off);
                }
                // f(tau) >= 0  <=>  sum >= 1
                const int cc = (f1 >= 1.f) + (f2 >= 1.f) + (f3 >= 1.f);
                lo = lo + w * (float)cc;
                hi = lo + w;
            }
            const float tau = 0.5f * (lo + hi);
            float S1 = 0.f, SX = 0.f, S3 = 0.f;
            for (int i = lane; i < total; i += 64) {
                const float x = cand[i];
                const float d = fmaxf(x - tau, 0.f);
                const float q = d * d;
                S1 += q;                 // sum p_unnorm
                SX = fmaf(q, x, SX);     // sum p_unnorm * Xs
                S3 = fmaf(q, d, S3);     // sum d^3 (for p^1.5)
            }
            #pragma unroll
            for (int off = 32; off > 0; off >>= 1) {
                S1 += __shfl_xor(S1, off);
                SX += __shfl_xor(SX, off);
                S3 += __shfl_xor(S3, off);
            }
            if (lane == 0) {
                // omega = (1 - sum p^1.5)/0.75;  sum p^1.5 = S3 / S1^1.5
                const float omega = (1.f - S3 / (S1 * sqrtf(S1))) * (4.f / 3.f);
                // sum p*X = 2*SX/S1 ;  loss = omega + sum(p*X) - X[target]
                const int tg = target[r];
                row_loss[r] = omega + 2.f * SX / S1 - Xr[tg];
            }
        }
        // other waves fall through to end (no further barriers on this path)
    } else {
        // ---- overflow fallback (never expected): recompute from global ----
        float lo = t0, hi = mx;
        for (int it = 0; it < NITER; ++it) {
            const float w  = (hi - lo) * 0.25f;
            const float t1 = lo + w, t2 = lo + 2.0f * w, t3 = lo + 3.0f * w;
            float f1 = 0.f, f2 = 0.f, f3 = 0.f;
            for (int i = tid; i < c; i += NTHR) {
                const float x = 0.5f * Xr[i];
                const float d1 = fmaxf(x - t1, 0.f); f1 = fmaf(d1, d1, f1);
                const float d2 = fmaxf(x - t2, 0.f); f2 = fmaf(d2, d2, f2);
                const float d3 = fmaxf(x - t3, 0.f); f3 = fmaf(d3, d3, f3);
            }
            #pragma unroll
            for (int off = 32; off > 0; off >>= 1) {
                f1 += __shfl_xor(f1, off);
                f2 += __shfl_xor(f2, off);
                f3 += __shfl_xor(f3, off);
            }
            if (lane == 0) { s_r3[0][wave] = f1; s_r3[1][wave] = f2; s_r3[2][wave] = f3; }
            __syncthreads();
            if (tid == 0) {
                float a = 0.f, b = 0.f, g = 0.f;
                for (int i = 0; i < 16; ++i) { a += s_r3[0][i]; b += s_r3[1][i]; g += s_r3[2][i]; }
                s_bcast[0] = a; s_bcast[1] = b; s_bcast[2] = g;
            }
            __syncthreads();
            const int cc = (s_bcast[0] >= 1.f) + (s_bcast[1] >= 1.f) + (s_bcast[2] >= 1.f);
            lo = lo + w * (float)cc;
            hi = lo + w;
        }
        const float tau = 0.5f * (lo + hi);
        float S1 = 0.f, SX = 0.f, S3 = 0.f;
        for (int i = tid; i < c; i += NTHR) {
            const float x = 0.5f * Xr[i];
            const float d = fmaxf(x - tau, 0.f);
            const float q = d * d;
            S1 += q; SX = fmaf(q, x, SX); S3 = fmaf(q, d, S3);
        }
        #pragma unroll
        for (int off = 32; off > 0; off >>= 1) {
            S1 += __shfl_xor(S1, off);
            SX += __shfl_xor(SX, off);
            S3 += __shfl_xor(S3, off);
        }
        if (lane == 0) { s_r3[0][wave] = S1; s_r3[1][wave] = SX; s_r3[2][wave] = S3; }
        __syncthreads();
        if (tid == 0) {
            float a = 0.f, b = 0.f, g = 0.f;
            for (int i = 0; i < 16; ++i) { a += s_r3[0][i]; b += s_r3[1][i]; g += s_r3[2][i]; }
            const float omega = (1.f - g / (a * sqrtf(a))) * (4.f / 3.f);
            const int tg = target[r];
            row_loss[r] = omega + 2.f * b / a - Xr[tg];
        }
    }
}

__global__ __launch_bounds__(NTHR)
void reduce_mean_kernel(const float* __restrict__ vv, float* __restrict__ out, int n) {
    __shared__ float s_red[16];
    float s = 0.f;
    for (int i = threadIdx.x; i < n; i += NTHR) s += vv[i];
    #pragma unroll
    for (int off = 32; off > 0; off >>= 1) s += __shfl_xor(s, off);
    const int wave = threadIdx.x >> 6;
    const int lane = threadIdx.x & 63;
    if (lane == 0) s_red[wave] = s;
    __syncthreads();
    if (threadIdx.x == 0) {
        float t = 0.f;
        for (int i = 0; i < 16; ++i) t += s_red[i];
        out[0] = t / (float)n;
    }
}

extern "C" void kernel_launch(void* const* d_in, const int* in_sizes, int n_in,
                              void* d_out, int out_size, void* d_ws, size_t ws_size,
                              hipStream_t stream) {
    const float* X      = (const float*)d_in[0];
    const int*   target = (const int*)d_in[1];
    float*       out    = (float*)d_out;
    float*       row_loss = (float*)d_ws;

    const int n = in_sizes[1];
    const int c = in_sizes[0] / n;

    entmax_row_kernel<<<n, NTHR, 0, stream>>>(X, target, row_loss, c);
    reduce_mean_kernel<<<1, NTHR, 0, stream>>>(row_loss, out, n);
}